// Round 2
// baseline (505.109 us; speedup 1.0000x reference)
//
#include <hip/hip_runtime.h>
#include <math.h>

// FlowLevel: DIM=2, half=1 -> per-layer coupling depends on scalar v = z_b.
// t(v) and u(v) (pre-sigmoid) are piecewise-LINEAR in v (ReLU MLP).
// Tabulate (t, dt/dv, u, du/dv) per node; reconstruct with two tangent
// lines (exact for <=1 kink per cell). sigmoid/log-sigmoid computed exactly
// in the apply kernel from reconstructed u.

constexpr int kDepth = 10;
constexpr int kWidth = 128;
constexpr float kVMin = -24.0f;
constexpr float kVMax =  24.0f;

// ---------------- table build: one MLP eval (+ forward-mode deriv) per thread ----------------
__global__ __launch_bounds__(256) void build_tables_kernel(
    const float* __restrict__ an_scale,
    const float* __restrict__ conv_w,
    const float* __restrict__ fc1_w, const float* __restrict__ fc1_b,
    const float* __restrict__ an1_scale, const float* __restrict__ an1_bias,
    const float* __restrict__ fc2_w, const float* __restrict__ fc2_b,
    const float* __restrict__ an2_scale, const float* __restrict__ an2_bias,
    const float* __restrict__ fc3_w, const float* __restrict__ fc3_b,
    const float* __restrict__ lsf,
    int tabN,
    float4* __restrict__ tab, float* __restrict__ extra)
{
  const int blocksPerLayer = tabN >> 8;
  const int layer = blockIdx.x / blocksPerLayer;
  const int q = (blockIdx.x % blocksPerLayer) * 256 + threadIdx.x;
  const float dv = (kVMax - kVMin) / (float)(tabN - 1);
  const float v = kVMin + dv * (float)q;

  const float* w1 = fc1_w + layer * kWidth;          // (128,1)
  const float* b1 = fc1_b + layer * kWidth;
  const float* s1 = an1_scale + layer * kWidth;
  const float* z1 = an1_bias + layer * kWidth;
  const float* w2 = fc2_w + layer * kWidth * kWidth; // (128,128), row k contiguous
  const float* b2 = fc2_b + layer * kWidth;
  const float* s2 = an2_scale + layer * kWidth;
  const float* z2 = an2_bias + layer * kWidth;
  const float* w3 = fc3_w + layer * 2 * kWidth;      // (2,128)
  const float* b3 = fc3_b + layer * 2;
  const float* lg = lsf + layer * 2;

  // h1_j = relu((v*w1_j + b1_j - z1_j)/s1_j); d1_j = dh1_j/dv
  float h1[kWidth];
  float d1[kWidth];
#pragma unroll
  for (int j = 0; j < kWidth; ++j) {
    float p = (fmaf(v, w1[j], b1[j]) - z1[j]) / s1[j];
    bool on = p > 0.0f;
    h1[j] = on ? p : 0.0f;
    d1[j] = on ? (w1[j] / s1[j]) : 0.0f;
  }

  // fc2 + fc3 fused, value+derivative together
  float o0 = 0.0f, o1 = 0.0f, p0 = 0.0f, p1 = 0.0f;
#pragma unroll 2
  for (int k = 0; k < kWidth; ++k) {
    const float* wr = w2 + k * kWidth;  // wave-uniform -> scalar loads
    float a0 = 0.f, a1 = 0.f, a2 = 0.f, a3 = 0.f;
    float c0 = 0.f, c1 = 0.f, c2 = 0.f, c3 = 0.f;
#pragma unroll
    for (int j = 0; j < kWidth; j += 4) {
      a0 = fmaf(h1[j+0], wr[j+0], a0);
      a1 = fmaf(h1[j+1], wr[j+1], a1);
      a2 = fmaf(h1[j+2], wr[j+2], a2);
      a3 = fmaf(h1[j+3], wr[j+3], a3);
      c0 = fmaf(d1[j+0], wr[j+0], c0);
      c1 = fmaf(d1[j+1], wr[j+1], c1);
      c2 = fmaf(d1[j+2], wr[j+2], c2);
      c3 = fmaf(d1[j+3], wr[j+3], c3);
    }
    float pre  = (((a0 + a1) + (a2 + a3)) + b2[k] - z2[k]) / s2[k];
    float dpre = (((c0 + c1) + (c2 + c3))) / s2[k];
    bool on = pre > 0.0f;
    float h2  = on ? pre : 0.0f;
    float dh2 = on ? dpre : 0.0f;
    o0 = fmaf(h2, w3[k], o0);
    p0 = fmaf(dh2, w3[k], p0);
    o1 = fmaf(h2, w3[kWidth + k], o1);
    p1 = fmaf(dh2, w3[kWidth + k], p1);
  }

  float E0 = expf(lg[0]);
  float E1 = expf(lg[1]);
  float t  = (o0 + b3[0]) * E0;
  float dt = p0 * E0;
  float u  = (o1 + b3[1]) * E1;
  float du = p1 * E1;

  tab[layer * tabN + q] = make_float4(t, dt, u, du);

  // sample-independent logdet constant
  if (blockIdx.x == 0 && threadIdx.x == 0) {
    float c = 0.0f;
    for (int i = 0; i < kDepth; ++i) {
      c -= logf(fabsf(an_scale[i*2+0]));
      c -= logf(fabsf(an_scale[i*2+1]));
      const float* cw = conv_w + i * 4;
      float det = cw[0]*cw[3] - cw[1]*cw[2];
      c += logf(fabsf(det));   // slogdet(conv)[1]
    }
    extra[0] = c;
  }
}

// ---------------- main: per-sample 10-layer loop with two-line reconstruction ----------------
__global__ __launch_bounds__(256) void flow_apply_kernel(
    const float* __restrict__ x,
    const float* __restrict__ an_scale, const float* __restrict__ an_bias,
    const float* __restrict__ conv_w,
    const float4* __restrict__ tab, const float* __restrict__ extra,
    int tabN,
    float* __restrict__ out_z, float* __restrict__ out_ld, int n)
{
  int idx = blockIdx.x * blockDim.x + threadIdx.x;
  if (idx >= n) return;

  float2 z = reinterpret_cast<const float2*>(x)[idx];
  float ld = extra[0];
  const float dv = (kVMax - kVMin) / (float)(tabN - 1);
  const float inv_dv = (float)(tabN - 1) / (kVMax - kVMin);

#pragma unroll
  for (int i = 0; i < kDepth; ++i) {
    // actnorm
    float za = (z.x - an_bias[i*2+0]) / an_scale[i*2+0];
    float zb = (z.y - an_bias[i*2+1]) / an_scale[i*2+1];
    // 1x1 conv (2x2): z' = W z
    const float* cw = conv_w + i*4;
    float na = fmaf(cw[0], za, cw[1]*zb);
    float nb = fmaf(cw[2], za, cw[3]*zb);
    // table cell
    float xq = (nb - kVMin) * inv_dv;
    int qi = (int)floorf(xq);
    qi = qi < 0 ? 0 : (qi > tabN-2 ? tabN-2 : qi);
    float v0 = fmaf((float)qi, dv, kVMin);
    float v1 = v0 + dv;
    float4 e0 = tab[i*tabN + qi];
    float4 e1 = tab[i*tabN + qi + 1];
    // two-tangent-line reconstruction (exact for <=1 kink per cell)
    float tL = fmaf(nb - v0, e0.y, e0.x);
    float tR = fmaf(nb - v1, e1.y, e1.x);
    float tt = (e1.y >= e0.y) ? fmaxf(tL, tR) : fminf(tL, tR);
    float uL = fmaf(nb - v0, e0.w, e0.z);
    float uR = fmaf(nb - v1, e1.w, e1.z);
    float uu = (e1.w >= e0.w) ? fmaxf(uL, uR) : fminf(uL, uR);
    // exact sigmoid / log-sigmoid of a = u + 2
    float a = uu + 2.0f;
    float e = expf(-a);
    float s = 1.0f / (1.0f + e);
    float lsv = -logf(1.0f + e);
    // coupling
    z.x = fmaf(s, na, tt);
    z.y = nb;
    ld += lsv;
  }

  reinterpret_cast<float2*>(out_z)[idx] = z;
  out_ld[idx] = ld;
}

extern "C" void kernel_launch(void* const* d_in, const int* in_sizes, int n_in,
                              void* d_out, int out_size, void* d_ws, size_t ws_size,
                              hipStream_t stream) {
  const float* x         = (const float*)d_in[0];
  const float* an_scale  = (const float*)d_in[1];
  const float* an_bias   = (const float*)d_in[2];
  const float* conv_w    = (const float*)d_in[3];
  const float* fc1_w     = (const float*)d_in[4];
  const float* fc1_b     = (const float*)d_in[5];
  const float* an1_scale = (const float*)d_in[6];
  const float* an1_bias  = (const float*)d_in[7];
  const float* fc2_w     = (const float*)d_in[8];
  const float* fc2_b     = (const float*)d_in[9];
  const float* an2_scale = (const float*)d_in[10];
  const float* an2_bias  = (const float*)d_in[11];
  const float* fc3_w     = (const float*)d_in[12];
  const float* fc3_b     = (const float*)d_in[13];
  const float* lsf       = (const float*)d_in[14];

  const int n = in_sizes[0] / 2;

  // workspace layout: [extra: 16 floats][table: float4 x kDepth x tabN]
  int tabN = 16384;
  while (tabN > 2048 &&
         (size_t)64 + (size_t)kDepth * tabN * sizeof(float4) > ws_size) {
    tabN >>= 1;
  }
  float* extra = (float*)d_ws;
  float4* tab  = (float4*)((char*)d_ws + 64);

  build_tables_kernel<<<kDepth * (tabN / 256), 256, 0, stream>>>(
      an_scale, conv_w, fc1_w, fc1_b, an1_scale, an1_bias,
      fc2_w, fc2_b, an2_scale, an2_bias, fc3_w, fc3_b, lsf, tabN, tab, extra);

  float* out_z  = (float*)d_out;
  float* out_ld = out_z + (size_t)2 * n;
  flow_apply_kernel<<<(n + 255) / 256, 256, 0, stream>>>(
      x, an_scale, an_bias, conv_w, tab, extra, tabN, out_z, out_ld, n);
}

// Round 3
// 365.624 us; speedup vs baseline: 1.3815x; 1.3815x over previous
//
#include <hip/hip_runtime.h>
#include <math.h>

// FlowLevel: DIM=2, half=1 -> per-layer coupling depends on scalar v = z_b.
// t(v) and u(v) (pre-sigmoid) are piecewise-LINEAR in v (ReLU MLP).
// Tabulate (t, dt/dv, u, du/dv) per node; reconstruct with two tangent
// lines (exact for <=1 kink per cell). sigmoid/log-sigmoid computed exactly
// in the apply kernel from reconstructed u.
//
// Build kernel v2: block-cooperative. 64 nodes/block, h1 staged in LDS
// (no per-thread 128-float arrays -> no scratch spills), d1 derived on the
// fly from sign(h1) * (w1/s1). Thread tile: 4 nodes x 8 k, value+deriv
// accumulators fully unrolled (static indexing).

constexpr int kDepth = 10;
constexpr int kWidth = 128;
constexpr float kVMin = -24.0f;
constexpr float kVMax =  24.0f;

__global__ __launch_bounds__(256) void build_tables_kernel(
    const float* __restrict__ an_scale,
    const float* __restrict__ conv_w,
    const float* __restrict__ fc1_w, const float* __restrict__ fc1_b,
    const float* __restrict__ an1_scale, const float* __restrict__ an1_bias,
    const float* __restrict__ fc2_w, const float* __restrict__ fc2_b,
    const float* __restrict__ an2_scale, const float* __restrict__ an2_bias,
    const float* __restrict__ fc3_w, const float* __restrict__ fc3_b,
    const float* __restrict__ lsf,
    int tabN,
    float4* __restrict__ tab, float* __restrict__ extra)
{
  __shared__ float4 sW1s[32];          // w1/s1, as 32 float4 chunks
  __shared__ float4 sBb[32];           // (b1-z1)/s1
  __shared__ float  sH[64][132];       // h1 tile, padded stride (2-way only)
  __shared__ float  sB2z[128], sS2i[128], sW3a[128], sW3b[128];

  const int bpl   = tabN >> 6;                 // blocks per layer
  const int layer = blockIdx.x / bpl;
  const int node0 = (blockIdx.x % bpl) * 64;
  const int tid   = threadIdx.x;
  const float dv  = (kVMax - kVMin) / (float)(tabN - 1);

  // ---- phase 0: layer-uniform constants into LDS ----
  if (tid < 128) {
    const int j = tid;
    const float inv1 = 1.0f / an1_scale[layer*kWidth + j];
    ((float*)sW1s)[j] = fc1_w[layer*kWidth + j] * inv1;
    ((float*)sBb)[j]  = (fc1_b[layer*kWidth + j] - an1_bias[layer*kWidth + j]) * inv1;
    sB2z[j] = fc2_b[layer*kWidth + j] - an2_bias[layer*kWidth + j];
    sS2i[j] = 1.0f / an2_scale[layer*kWidth + j];
    sW3a[j] = fc3_w[layer*2*kWidth + j];
    sW3b[j] = fc3_w[layer*2*kWidth + kWidth + j];
  }
  __syncthreads();

  // ---- phase 1: fill h1 tile (64 nodes x 128 j) ----
  {
    const int node = tid >> 2;            // 0..63
    const int cq0  = (tid & 3) * 8;       // float4 chunk base 0,8,16,24
    const float v = kVMin + dv * (float)(node0 + node);
#pragma unroll
    for (int c = 0; c < 8; ++c) {
      float4 w = sW1s[cq0 + c];
      float4 b = sBb[cq0 + c];
      float4 h;
      h.x = fmaxf(fmaf(v, w.x, b.x), 0.0f);
      h.y = fmaxf(fmaf(v, w.y, b.y), 0.0f);
      h.z = fmaxf(fmaf(v, w.z, b.z), 0.0f);
      h.w = fmaxf(fmaf(v, w.w, b.w), 0.0f);
      *(float4*)&sH[node][(cq0 + c) * 4] = h;
    }
  }
  __syncthreads();

  // ---- phase 2: fused fc2 value+deriv dots ----
  const int kg = tid & 15;   // k-group: k = kg*8 + kk
  const int ng = tid >> 4;   // node-group: node = ng*4 + nn
  const float4* __restrict__ w2base =
      (const float4*)(fc2_w + (size_t)layer * kWidth * kWidth + (size_t)kg * 8 * kWidth);

  float a[4][8];   // value dots
  float c[4][8];   // deriv dots
#pragma unroll
  for (int nn = 0; nn < 4; ++nn)
#pragma unroll
    for (int kk = 0; kk < 8; ++kk) { a[nn][kk] = 0.0f; c[nn][kk] = 0.0f; }

  for (int jc = 0; jc < 32; ++jc) {
    float4 wg = sW1s[jc];                        // broadcast
    float4 h4[4], d4[4];
#pragma unroll
    for (int nn = 0; nn < 4; ++nn) {
      float4 h = *(const float4*)&sH[ng*4 + nn][jc*4];
      h4[nn] = h;
      d4[nn].x = (h.x > 0.0f) ? wg.x : 0.0f;
      d4[nn].y = (h.y > 0.0f) ? wg.y : 0.0f;
      d4[nn].z = (h.z > 0.0f) ? wg.z : 0.0f;
      d4[nn].w = (h.w > 0.0f) ? wg.w : 0.0f;
    }
#pragma unroll
    for (int kk = 0; kk < 8; ++kk) {
      float4 w = w2base[kk*32 + jc];             // L1-hot, 16-lane broadcast
#pragma unroll
      for (int nn = 0; nn < 4; ++nn) {
        float av = a[nn][kk];
        av = fmaf(h4[nn].x, w.x, av);
        av = fmaf(h4[nn].y, w.y, av);
        av = fmaf(h4[nn].z, w.z, av);
        av = fmaf(h4[nn].w, w.w, av);
        a[nn][kk] = av;
        float cv = c[nn][kk];
        cv = fmaf(d4[nn].x, w.x, cv);
        cv = fmaf(d4[nn].y, w.y, cv);
        cv = fmaf(d4[nn].z, w.z, cv);
        cv = fmaf(d4[nn].w, w.w, cv);
        c[nn][kk] = cv;
      }
    }
  }

  // ---- phase 3: relu + fc3 partials, reduce over kg, write ----
  float o0[4] = {0,0,0,0}, o1[4] = {0,0,0,0};
  float p0[4] = {0,0,0,0}, p1[4] = {0,0,0,0};
#pragma unroll
  for (int kk = 0; kk < 8; ++kk) {
    const int k = kg*8 + kk;
    const float bz = sB2z[k], si = sS2i[k], wa = sW3a[k], wb = sW3b[k];
#pragma unroll
    for (int nn = 0; nn < 4; ++nn) {
      float pre  = (a[nn][kk] + bz) * si;
      float dpre = c[nn][kk] * si;
      bool  on   = pre > 0.0f;
      float h2   = on ? pre  : 0.0f;
      float dh2  = on ? dpre : 0.0f;
      o0[nn] = fmaf(h2,  wa, o0[nn]);
      p0[nn] = fmaf(dh2, wa, p0[nn]);
      o1[nn] = fmaf(h2,  wb, o1[nn]);
      p1[nn] = fmaf(dh2, wb, p1[nn]);
    }
  }
#pragma unroll
  for (int off = 8; off >= 1; off >>= 1) {
#pragma unroll
    for (int nn = 0; nn < 4; ++nn) {
      o0[nn] += __shfl_xor(o0[nn], off);
      o1[nn] += __shfl_xor(o1[nn], off);
      p0[nn] += __shfl_xor(p0[nn], off);
      p1[nn] += __shfl_xor(p1[nn], off);
    }
  }
  if (kg == 0) {
    const float E0 = expf(lsf[layer*2 + 0]);
    const float E1 = expf(lsf[layer*2 + 1]);
    const float b30 = fc3_b[layer*2 + 0];
    const float b31 = fc3_b[layer*2 + 1];
#pragma unroll
    for (int nn = 0; nn < 4; ++nn) {
      const int q = node0 + ng*4 + nn;
      tab[(size_t)layer * tabN + q] =
          make_float4((o0[nn] + b30) * E0, p0[nn] * E0,
                      (o1[nn] + b31) * E1, p1[nn] * E1);
    }
  }

  // sample-independent logdet constant
  if (blockIdx.x == 0 && tid == 0) {
    float cst = 0.0f;
    for (int i = 0; i < kDepth; ++i) {
      cst -= logf(fabsf(an_scale[i*2+0]));
      cst -= logf(fabsf(an_scale[i*2+1]));
      const float* cw = conv_w + i * 4;
      float det = cw[0]*cw[3] - cw[1]*cw[2];
      cst += logf(fabsf(det));   // slogdet(conv)[1]
    }
    extra[0] = cst;
  }
}

// ---------------- main: per-sample 10-layer loop with two-line reconstruction ----------------
__global__ __launch_bounds__(256) void flow_apply_kernel(
    const float* __restrict__ x,
    const float* __restrict__ an_scale, const float* __restrict__ an_bias,
    const float* __restrict__ conv_w,
    const float4* __restrict__ tab, const float* __restrict__ extra,
    int tabN,
    float* __restrict__ out_z, float* __restrict__ out_ld, int n)
{
  int idx = blockIdx.x * blockDim.x + threadIdx.x;
  if (idx >= n) return;

  float2 z = reinterpret_cast<const float2*>(x)[idx];
  float ld = extra[0];
  const float dv = (kVMax - kVMin) / (float)(tabN - 1);
  const float inv_dv = (float)(tabN - 1) / (kVMax - kVMin);

#pragma unroll
  for (int i = 0; i < kDepth; ++i) {
    // actnorm
    float za = (z.x - an_bias[i*2+0]) / an_scale[i*2+0];
    float zb = (z.y - an_bias[i*2+1]) / an_scale[i*2+1];
    // 1x1 conv (2x2): z' = W z
    const float* cw = conv_w + i*4;
    float na = fmaf(cw[0], za, cw[1]*zb);
    float nb = fmaf(cw[2], za, cw[3]*zb);
    // table cell
    float xq = (nb - kVMin) * inv_dv;
    int qi = (int)floorf(xq);
    qi = qi < 0 ? 0 : (qi > tabN-2 ? tabN-2 : qi);
    float v0 = fmaf((float)qi, dv, kVMin);
    float v1 = v0 + dv;
    float4 e0 = tab[(size_t)i*tabN + qi];
    float4 e1 = tab[(size_t)i*tabN + qi + 1];
    // two-tangent-line reconstruction (exact for <=1 kink per cell)
    float tL = fmaf(nb - v0, e0.y, e0.x);
    float tR = fmaf(nb - v1, e1.y, e1.x);
    float tt = (e1.y >= e0.y) ? fmaxf(tL, tR) : fminf(tL, tR);
    float uL = fmaf(nb - v0, e0.w, e0.z);
    float uR = fmaf(nb - v1, e1.w, e1.z);
    float uu = (e1.w >= e0.w) ? fmaxf(uL, uR) : fminf(uL, uR);
    // exact sigmoid / log-sigmoid of arg = u + 2
    float arg = uu + 2.0f;
    float e = expf(-arg);
    float s = 1.0f / (1.0f + e);
    float lsv = -logf(1.0f + e);
    // coupling
    z.x = fmaf(s, na, tt);
    z.y = nb;
    ld += lsv;
  }

  reinterpret_cast<float2*>(out_z)[idx] = z;
  out_ld[idx] = ld;
}

extern "C" void kernel_launch(void* const* d_in, const int* in_sizes, int n_in,
                              void* d_out, int out_size, void* d_ws, size_t ws_size,
                              hipStream_t stream) {
  const float* x         = (const float*)d_in[0];
  const float* an_scale  = (const float*)d_in[1];
  const float* an_bias   = (const float*)d_in[2];
  const float* conv_w    = (const float*)d_in[3];
  const float* fc1_w     = (const float*)d_in[4];
  const float* fc1_b     = (const float*)d_in[5];
  const float* an1_scale = (const float*)d_in[6];
  const float* an1_bias  = (const float*)d_in[7];
  const float* fc2_w     = (const float*)d_in[8];
  const float* fc2_b     = (const float*)d_in[9];
  const float* an2_scale = (const float*)d_in[10];
  const float* an2_bias  = (const float*)d_in[11];
  const float* fc3_w     = (const float*)d_in[12];
  const float* fc3_b     = (const float*)d_in[13];
  const float* lsf       = (const float*)d_in[14];

  const int n = in_sizes[0] / 2;

  // workspace layout: [extra: 16 floats][table: float4 x kDepth x tabN]
  int tabN = 16384;
  while (tabN > 2048 &&
         (size_t)64 + (size_t)kDepth * tabN * sizeof(float4) > ws_size) {
    tabN >>= 1;
  }
  float* extra = (float*)d_ws;
  float4* tab  = (float4*)((char*)d_ws + 64);

  build_tables_kernel<<<kDepth * (tabN / 64), 256, 0, stream>>>(
      an_scale, conv_w, fc1_w, fc1_b, an1_scale, an1_bias,
      fc2_w, fc2_b, an2_scale, an2_bias, fc3_w, fc3_b, lsf, tabN, tab, extra);

  float* out_z  = (float*)d_out;
  float* out_ld = out_z + (size_t)2 * n;
  flow_apply_kernel<<<(n + 255) / 256, 256, 0, stream>>>(
      x, an_scale, an_bias, conv_w, tab, extra, tabN, out_z, out_ld, n);
}